// Round 12
// baseline (89.010 us; speedup 1.0000x reference)
//
#include <hip/hip_runtime.h>
#include <math.h>

// NG=4, N=6, NFG=8, NFR=256, NACT=5, B=32768
// sim factorization: sim[g,n,m] = (f_n^T M_g f_m + U_g.f_n + V_g.f_m + C_g)/16
// ws layout (floats), R2/R6-proven, UNSCALED:
//   M[g*64+f1*8+f2] @0, U[g*8+f] @256, V[g*8+f] @288, C[g] @320   (324 floats)

// ===== R6/R9's precompute, VERBATIM (proven) =====
__launch_bounds__(256)
__global__ void gcn_precompute(const float* __restrict__ Wt, const float* __restrict__ bt,
                               const float* __restrict__ Wp, const float* __restrict__ bp,
                               float* __restrict__ ws) {
  const int wave = threadIdx.x >> 6, lane = threadIdx.x & 63;
  const int tau = blockIdx.x * 4 + wave;  // 81*4 = 324 exactly
  const float *cA, *cB;
  int sA, sB;
  if (tau < 256) {            // M[g][f1][f2] = sum_r Wt[g,r,f1]*Wp[g,r,f2]
    const int g = tau >> 6, f1 = (tau >> 3) & 7, f2 = tau & 7;
    cA = Wt + g * 2048 + f1; sA = 8;
    cB = Wp + g * 2048 + f2; sB = 8;
  } else if (tau < 288) {     // U[g][f] = sum_r Wt[g,r,f]*bp[g,r]
    const int i = tau - 256, g = i >> 3, f = i & 7;
    cA = Wt + g * 2048 + f;  sA = 8;
    cB = bp + g * 256;       sB = 1;
  } else if (tau < 320) {     // V[g][f] = sum_r Wp[g,r,f]*bt[g,r]
    const int i = tau - 288, g = i >> 3, f = i & 7;
    cA = Wp + g * 2048 + f;  sA = 8;
    cB = bt + g * 256;       sB = 1;
  } else {                    // C[g] = sum_r bt[g,r]*bp[g,r]
    const int g = tau - 320;
    cA = bt + g * 256; sA = 1;
    cB = bp + g * 256; sB = 1;
  }
  float s = 0.0f;
#pragma unroll
  for (int i = 0; i < 4; ++i) {
    const int r = lane + 64 * i;
    s = fmaf(cA[r * sA], cB[r * sB], s);
  }
#pragma unroll
  for (int off = 1; off < 64; off <<= 1) s += __shfl_xor(s, off, 64);
  if (lane == 0) ws[tau] = s;
}

// ---- DPP quad_perm helpers ----
template <int CTRL>
__device__ __forceinline__ float qperm_f(float v) {
  return __int_as_float(
      __builtin_amdgcn_update_dpp(0, __float_as_int(v), CTRL, 0xF, 0xF, true));
}
template <int CTRL>
__device__ __forceinline__ unsigned qperm_u(unsigned v) {
  return (unsigned)__builtin_amdgcn_update_dpp(0, (int)v, CTRL, 0xF, 0xF, true);
}

// ---- packed fp32 FMA: two independent fmaf per instruction (VOP3P) ----
__device__ __forceinline__ float2 pk_fma(float2 a, float2 b, float2 c) {
  float2 d;
  asm("v_pk_fma_f32 %0, %1, %2, %3" : "=v"(d) : "v"(a), "v"(b), "v"(c));
  return d;
}
__device__ __forceinline__ float2 bc2(float x) { return make_float2(x, x); }

// ===== R9 base + packed-FP32 dot blocks. block=256, 4 lanes/element. =====
__launch_bounds__(256, 2)
__global__ void gcn_main(const float* __restrict__ bfeat, const float* __restrict__ pos,
                         const float* __restrict__ W_ext, const float* __restrict__ b_ext,
                         const float* __restrict__ W_gcn, const float* __restrict__ W_act,
                         const float* __restrict__ b_act, const float* __restrict__ ws,
                         float* __restrict__ out, int B) {
  __shared__ __align__(16) float sWext[64];
  __shared__ float sbext[8];
  // sM: interleaved row-pairs: (float2*)(sM+g*68)[p*8+f2] = {M[2p][f2], M[2p+1][f2]}
  __shared__ __align__(16) float sM[4 * 68];
  __shared__ __align__(16) float sU[4 * 12];
  __shared__ __align__(16) float sV[4 * 12];
  __shared__ float sC[4];
  __shared__ __align__(16) float sWgcn[4 * 68];  // row-major, pre-scaled by 0.25
  __shared__ float sWact[40];
  __shared__ float sbact[5];

  const int tid = threadIdx.x;
  if (tid < 64) sWext[tid] = W_ext[tid];
  if (tid < 8) sbext[tid] = b_ext[tid];
  {  // M staged into interleaved-pair layout
    const int g1 = tid >> 6, r = tid & 63, f1 = r >> 3, f2 = r & 7;
    sM[g1 * 68 + (((f1 >> 1) * 8 + f2) << 1) + (f1 & 1)] = ws[tid];
  }
  if (tid < 32) sU[(tid >> 3) * 12 + (tid & 7)] = ws[256 + tid];
  if (tid < 32) sV[(tid >> 3) * 12 + (tid & 7)] = ws[288 + tid];
  if (tid < 4) sC[tid] = ws[320 + tid];
  sWgcn[(tid >> 6) * 68 + (tid & 63)] = 0.25f * W_gcn[tid];
  if (tid < 40) sWact[tid] = W_act[tid];
  if (tid < 5) sbact[tid] = b_act[tid];
  __syncthreads();

  const int e = blockIdx.x * 64 + (tid >> 2);  // batch element
  const int g = tid & 3;                       // relation group
  if (e >= B) return;

  // ---- load positions [6][2] ----
  float px[6], py[6];
  {
    const float4* p4 = (const float4*)(pos + (size_t)e * 12);
    float4 p0 = p4[0], p1 = p4[1], p2 = p4[2];
    px[0] = p0.x; py[0] = p0.y; px[1] = p0.z; py[1] = p0.w;
    px[2] = p1.x; py[2] = p1.y; px[3] = p1.z; py[3] = p1.w;
    px[4] = p2.x; py[4] = p2.y; px[5] = p2.z; py[5] = p2.w;
  }

  // ---- load raw features as pairs bf2[n][p] = {bf[2p], bf[2p+1]} ----
  float2 bf2[6][4];
  {
    const float4* f4 = (const float4*)(bfeat + (size_t)e * 48);
#pragma unroll
    for (int i = 0; i < 12; ++i) {
      float4 v = f4[i];
      const int n = i >> 1, base = (i & 1) * 2;
      bf2[n][base + 0] = make_float2(v.x, v.y);
      bf2[n][base + 1] = make_float2(v.z, v.w);
    }
  }

  // ---- position mask, 4-way split across the quad (R8/R9 VERBATIM — do not touch) ----
  float rr[6];
#pragma unroll
  for (int n = 0; n < 6; ++n)
    rr[n] = __fadd_rn(__fmul_rn(px[n], px[n]), __fmul_rn(py[n], py[n]));
  unsigned long long mask;
  {
    const int h2 = (g >> 1) & 1, q2 = g & 1;
    float pxn[3], pyn[3], rrn[3], pxm[3], pym[3], rrm[3];
#pragma unroll
    for (int k = 0; k < 3; ++k) {
      pxn[k] = h2 ? px[k + 3] : px[k];
      pyn[k] = h2 ? py[k + 3] : py[k];
      rrn[k] = h2 ? rr[k + 3] : rr[k];
      pxm[k] = q2 ? px[k + 3] : px[k];
      pym[k] = q2 ? py[k + 3] : py[k];
      rrm[k] = q2 ? rr[k + 3] : rr[k];
    }
    unsigned long long part = 0ull;
    const int rbase = 3 * h2, mbase = 3 * q2;
#pragma unroll
    for (int k = 0; k < 3; ++k) {
#pragma unroll
      for (int j = 0; j < 3; ++j) {
        float dot = __fadd_rn(__fmul_rn(pxn[k], pxm[j]), __fmul_rn(pyn[k], pym[j]));
        float d2 = __fadd_rn(__fsub_rn(rrn[k], __fmul_rn(2.0f, dot)), rrm[j]);
        float dist = sqrtf(d2);  // exact numpy fp32 sequence; diag NaN -> false
        if (dist > 4.0f) part |= (1ull << ((rbase + k) * 6 + (mbase + j)));
      }
    }
    unsigned lo = (unsigned)part, hi = (unsigned)(part >> 32);
    lo |= qperm_u<0xB1>(lo); hi |= qperm_u<0xB1>(hi);
    lo |= qperm_u<0x4E>(lo); hi |= qperm_u<0x4E>(hi);
    mask = (unsigned long long)lo | ((unsigned long long)hi << 32);
  }

  // ---- feature extension (packed dots), split across the 4 g-lanes ----
  float myo[6][2];
#pragma unroll
  for (int k = 0; k < 2; ++k) {
    const int o = 2 * g + k;
    const float4 w0 = *(const float4*)(sWext + o * 8);
    const float4 w1 = *(const float4*)(sWext + o * 8 + 4);
    const float2 wp[4] = {make_float2(w0.x, w0.y), make_float2(w0.z, w0.w),
                          make_float2(w1.x, w1.y), make_float2(w1.z, w1.w)};
    const float bo = sbext[o];
#pragma unroll
    for (int n = 0; n < 6; ++n) {
      float2 c = make_float2(bo, 0.0f);
#pragma unroll
      for (int p = 0; p < 4; ++p) c = pk_fma(bf2[n][p], wp[p], c);
      myo[n][k] = fmaxf(c.x + c.y, 0.0f);
    }
  }
  // all-gather feat pairs via DPP quad broadcasts (lane j holds o=2j,2j+1)
  float2 feat2[6][4];
#pragma unroll
  for (int n = 0; n < 6; ++n) {
    feat2[n][0] = make_float2(qperm_f<0x00>(myo[n][0]), qperm_f<0x00>(myo[n][1]));
    feat2[n][1] = make_float2(qperm_f<0x55>(myo[n][0]), qperm_f<0x55>(myo[n][1]));
    feat2[n][2] = make_float2(qperm_f<0xAA>(myo[n][0]), qperm_f<0xAA>(myo[n][1]));
    feat2[n][3] = make_float2(qperm_f<0xFF>(myo[n][0]), qperm_f<0xFF>(myo[n][1]));
  }

  // ---- con init: 0.25*bfr (4-lane sum contributes the residual exactly once) ----
  float con[6][8];
#pragma unroll
  for (int n = 0; n < 6; ++n)
#pragma unroll
    for (int p = 0; p < 4; ++p) {
      con[n][2 * p] = 0.25f * bf2[n][p].x;
      con[n][2 * p + 1] = 0.25f * bf2[n][p].y;
    }

  // ---- this lane's group tables ----
  const float2* Mg2 = (const float2*)(sM + g * 68);
  const float4* W4 = (const float4*)(sWgcn + g * 68);
  const float2* U2 = (const float2*)(sU + g * 12);
  const float2* V2 = (const float2*)(sV + g * 12);
  const float Cg = sC[g];

  // z2[m][p] = {z[m][2p], z[m][2p+1]}, z[m][f1] = sum_f2 M[f1][f2]*feat[m][f2]
  // (f2 ascending -> each scalar chain bitwise-identical to R9's z)
  float2 z2[6][4];
#pragma unroll
  for (int m = 0; m < 6; ++m)
#pragma unroll
    for (int p = 0; p < 4; ++p) z2[m][p] = make_float2(0.0f, 0.0f);
#pragma unroll
  for (int f2 = 0; f2 < 8; ++f2) {
    float2 fb[6];
#pragma unroll
    for (int m = 0; m < 6; ++m)
      fb[m] = bc2((f2 & 1) ? feat2[m][f2 >> 1].y : feat2[m][f2 >> 1].x);
#pragma unroll
    for (int p = 0; p < 4; ++p) {
      const float2 Mv = Mg2[p * 8 + f2];
#pragma unroll
      for (int m = 0; m < 6; ++m) z2[m][p] = pk_fma(Mv, fb[m], z2[m][p]);
    }
  }

  // uv/vv (packed dots)
  float uv[6], vv[6];
  {
    const float2 u[4] = {U2[0], U2[1], U2[2], U2[3]};
    const float2 v[4] = {V2[0], V2[1], V2[2], V2[3]};
#pragma unroll
    for (int n = 0; n < 6; ++n) {
      float2 cu = make_float2(0.0f, 0.0f), cv = make_float2(0.0f, 0.0f);
#pragma unroll
      for (int p = 0; p < 4; ++p) {
        cu = pk_fma(u[p], feat2[n][p], cu);
        cv = pk_fma(v[p], feat2[n][p], cv);
      }
      uv[n] = cu.x + cu.y; vv[n] = cv.x + cv.y;
    }
  }

  // sim + softmax -> P[6][6] (packed dots; R9's (s+uv+vv+Cg)*0.0625 shape)
  float P[6][6];
#pragma unroll
  for (int n = 0; n < 6; ++n) {
    float simr[6];
    float rmax = -INFINITY;
#pragma unroll
    for (int m = 0; m < 6; ++m) {
      float2 c = make_float2(0.0f, 0.0f);
#pragma unroll
      for (int p = 0; p < 4; ++p) c = pk_fma(feat2[n][p], z2[m][p], c);
      float s = ((c.x + c.y) + uv[n] + vv[m] + Cg) * 0.0625f;
      const bool msk = (mask >> (n * 6 + m)) & 1ull;
      simr[m] = msk ? -INFINITY : s;
      rmax = fmaxf(rmax, simr[m]);
    }
    float e6[6], esum = 0.0f;
#pragma unroll
    for (int m = 0; m < 6; ++m) {
      float ev = __expf(simr[m] - rmax);
      e6[m] = ev; esum += ev;
    }
    const float inv = 1.0f / esum;  // diag always unmasked
#pragma unroll
    for (int m = 0; m < 6; ++m) P[n][m] = e6[m] * inv;
  }

  // agg2[n][p] += P[n][m]*feat2[m][p]  (m ascending -> bitwise-identical to R9's agg)
  float2 agg2[6][4];
#pragma unroll
  for (int n = 0; n < 6; ++n)
#pragma unroll
    for (int p = 0; p < 4; ++p) agg2[n][p] = make_float2(0.0f, 0.0f);
#pragma unroll
  for (int m = 0; m < 6; ++m) {
#pragma unroll
    for (int n = 0; n < 6; ++n) {
      const float2 pb = bc2(P[n][m]);
#pragma unroll
      for (int p = 0; p < 4; ++p) agg2[n][p] = pk_fma(pb, feat2[m][p], agg2[n][p]);
    }
  }

  // con += relu(0.25*Wgcn_g @ agg)  (packed dots)
#pragma unroll
  for (int o = 0; o < 8; ++o) {
    const float4 a = W4[2 * o], b = W4[2 * o + 1];
    const float2 wp[4] = {make_float2(a.x, a.y), make_float2(a.z, a.w),
                          make_float2(b.x, b.y), make_float2(b.z, b.w)};
#pragma unroll
    for (int n = 0; n < 6; ++n) {
      float2 c = make_float2(0.0f, 0.0f);
#pragma unroll
      for (int p = 0; p < 4; ++p) c = pk_fma(wp[p], agg2[n][p], c);
      con[n][o] += fmaxf(c.x + c.y, 0.0f);
    }
  }

  // ---- butterfly-sum across the 4 g-lanes via DPP (xor1, xor2) ----
#pragma unroll
  for (int n = 0; n < 6; ++n)
#pragma unroll
    for (int f = 0; f < 8; ++f) {
      float v = con[n][f];
      v += qperm_f<0xB1>(v);
      v += qperm_f<0x4E>(v);
      con[n][f] = v;
    }

  // ---- epilogue ----
  float pooled[8];
#pragma unroll
  for (int f = 0; f < 8; ++f) {
    float mx = con[0][f];
#pragma unroll
    for (int n = 1; n < 6; ++n) mx = fmaxf(mx, con[n][f]);
    pooled[f] = mx;
  }
  float scg = sbact[g], sc4 = sbact[4];
#pragma unroll
  for (int f = 0; f < 8; ++f) {
    scg = fmaf(pooled[f], sWact[g * 8 + f], scg);
    sc4 = fmaf(pooled[f], sWact[4 * 8 + f], sc4);
  }
  const size_t ob = (size_t)e * 5;
  out[ob + g] = scg;
  if (g == 0) out[ob + 4] = sc4;
}

extern "C" void kernel_launch(void* const* d_in, const int* in_sizes, int n_in,
                              void* d_out, int out_size, void* d_ws, size_t ws_size,
                              hipStream_t stream) {
  const float* bfeat   = (const float*)d_in[0];
  const float* pos     = (const float*)d_in[1];
  const float* W_ext   = (const float*)d_in[2];
  const float* b_ext   = (const float*)d_in[3];
  const float* W_theta = (const float*)d_in[4];
  const float* b_theta = (const float*)d_in[5];
  const float* W_phi   = (const float*)d_in[6];
  const float* b_phi   = (const float*)d_in[7];
  const float* W_gcn   = (const float*)d_in[8];
  const float* W_act   = (const float*)d_in[9];
  const float* b_act   = (const float*)d_in[10];
  float* out = (float*)d_out;
  float* ws  = (float*)d_ws;

  const int B = in_sizes[0] / 48;  // [B,6,8]

  hipLaunchKernelGGL(gcn_precompute, dim3(81), dim3(256), 0, stream,
                     W_theta, b_theta, W_phi, b_phi, ws);
  const int grid = (B + 63) / 64;
  hipLaunchKernelGGL(gcn_main, dim3(grid), dim3(256), 0, stream,
                     bfeat, pos, W_ext, b_ext, W_gcn, W_act, b_act, ws, out, B);
}

// Round 13
// 87.920 us; speedup vs baseline: 1.0124x; 1.0124x over previous
//
#include <hip/hip_runtime.h>
#include <math.h>

// NG=4, N=6, NFG=8, NFR=256, NACT=5, B=32768
// sim factorization: sim[g,n,m] = (f_n^T M_g f_m + U_g.f_n + V_g.f_m + C_g)/16
// ws layout (floats), R2/R6-proven, UNSCALED:
//   M[g*64+f1*8+f2] @0, U[g*8+f] @256, V[g*8+f] @288, C[g] @320   (324 floats)
//
// R13 == R9 verbatim (best measured: 87.7 us, absmax 0.0078125).
// Post-R9 experiments (R10 const-fold/exp2/rcp, R11 block=128, R12 packed fp32)
// were all within-noise or regressions; reverted per rigor.

// ===== R6's precompute, VERBATIM (proven) =====
__launch_bounds__(256)
__global__ void gcn_precompute(const float* __restrict__ Wt, const float* __restrict__ bt,
                               const float* __restrict__ Wp, const float* __restrict__ bp,
                               float* __restrict__ ws) {
  const int wave = threadIdx.x >> 6, lane = threadIdx.x & 63;
  const int tau = blockIdx.x * 4 + wave;  // 81*4 = 324 exactly
  const float *cA, *cB;
  int sA, sB;
  if (tau < 256) {            // M[g][f1][f2] = sum_r Wt[g,r,f1]*Wp[g,r,f2]
    const int g = tau >> 6, f1 = (tau >> 3) & 7, f2 = tau & 7;
    cA = Wt + g * 2048 + f1; sA = 8;
    cB = Wp + g * 2048 + f2; sB = 8;
  } else if (tau < 288) {     // U[g][f] = sum_r Wt[g,r,f]*bp[g,r]
    const int i = tau - 256, g = i >> 3, f = i & 7;
    cA = Wt + g * 2048 + f;  sA = 8;
    cB = bp + g * 256;       sB = 1;
  } else if (tau < 320) {     // V[g][f] = sum_r Wp[g,r,f]*bt[g,r]
    const int i = tau - 288, g = i >> 3, f = i & 7;
    cA = Wp + g * 2048 + f;  sA = 8;
    cB = bt + g * 256;       sB = 1;
  } else {                    // C[g] = sum_r bt[g,r]*bp[g,r]
    const int g = tau - 320;
    cA = bt + g * 256; sA = 1;
    cB = bp + g * 256; sB = 1;
  }
  float s = 0.0f;
#pragma unroll
  for (int i = 0; i < 4; ++i) {
    const int r = lane + 64 * i;
    s = fmaf(cA[r * sA], cB[r * sB], s);
  }
#pragma unroll
  for (int off = 1; off < 64; off <<= 1) s += __shfl_xor(s, off, 64);
  if (lane == 0) ws[tau] = s;
}

// ---- DPP quad_perm helpers (element's 4 lanes are 4-aligned -> intra-quad) ----
// ctrl = p0 | p1<<2 | p2<<4 | p3<<6
//   xor1 [1,0,3,2] = 0xB1   xor2 [2,3,0,1] = 0x4E
//   bcast0 0x00  bcast1 0x55  bcast2 0xAA  bcast3 0xFF
template <int CTRL>
__device__ __forceinline__ float qperm_f(float v) {
  return __int_as_float(
      __builtin_amdgcn_update_dpp(0, __float_as_int(v), CTRL, 0xF, 0xF, true));
}
template <int CTRL>
__device__ __forceinline__ unsigned qperm_u(unsigned v) {
  return (unsigned)__builtin_amdgcn_update_dpp(0, (int)v, CTRL, 0xF, 0xF, true);
}

// ===== gcn_main: DPP cross-lane + float4 LDS reads (R9) =====
// block=256: 64 elements/block, 4 lanes (one per g) per element. grid = B/64.
__launch_bounds__(256, 2)
__global__ void gcn_main(const float* __restrict__ bfeat, const float* __restrict__ pos,
                         const float* __restrict__ W_ext, const float* __restrict__ b_ext,
                         const float* __restrict__ W_gcn, const float* __restrict__ W_act,
                         const float* __restrict__ b_act, const float* __restrict__ ws,
                         float* __restrict__ out, int B) {
  // strides: M/Wgcn 68 (16B-aligned rows; quad bank bases {0,4,8,12} -> conflict-free),
  //          U/V 12 (bank bases {0,12,24,4}); inter-quad reads are same-addr broadcasts.
  __shared__ __align__(16) float sWext[64];
  __shared__ float sbext[8];
  __shared__ __align__(16) float sM[4 * 68];
  __shared__ __align__(16) float sU[4 * 12];
  __shared__ __align__(16) float sV[4 * 12];
  __shared__ float sC[4];
  __shared__ __align__(16) float sWgcn[4 * 68];  // pre-scaled by 0.25
  __shared__ float sWact[40];
  __shared__ float sbact[5];

  const int tid = threadIdx.x;
  if (tid < 64) sWext[tid] = W_ext[tid];
  if (tid < 8) sbext[tid] = b_ext[tid];
  sM[(tid >> 6) * 68 + (tid & 63)] = ws[tid];
  if (tid < 32) sU[(tid >> 3) * 12 + (tid & 7)] = ws[256 + tid];
  if (tid < 32) sV[(tid >> 3) * 12 + (tid & 7)] = ws[288 + tid];
  if (tid < 4) sC[tid] = ws[320 + tid];
  sWgcn[(tid >> 6) * 68 + (tid & 63)] = 0.25f * W_gcn[tid];
  if (tid < 40) sWact[tid] = W_act[tid];
  if (tid < 5) sbact[tid] = b_act[tid];
  __syncthreads();

  const int e = blockIdx.x * 64 + (tid >> 2);  // batch element
  const int g = tid & 3;                       // relation group
  if (e >= B) return;

  // ---- load positions [6][2] ----
  float px[6], py[6];
  {
    const float4* p4 = (const float4*)(pos + (size_t)e * 12);
    float4 p0 = p4[0], p1 = p4[1], p2 = p4[2];
    px[0] = p0.x; py[0] = p0.y; px[1] = p0.z; py[1] = p0.w;
    px[2] = p1.x; py[2] = p1.y; px[3] = p1.z; py[3] = p1.w;
    px[4] = p2.x; py[4] = p2.y; px[5] = p2.z; py[5] = p2.w;
  }

  // ---- load raw features [6][8] ----
  float bfr[6][8];
  {
    const float4* f4 = (const float4*)(bfeat + (size_t)e * 48);
#pragma unroll
    for (int i = 0; i < 12; ++i) {
      float4 v = f4[i];
      const int n = i >> 1, base = (i & 1) * 4;
      bfr[n][base + 0] = v.x; bfr[n][base + 1] = v.y;
      bfr[n][base + 2] = v.z; bfr[n][base + 3] = v.w;
    }
  }

  // ---- position mask, 4-way split across the quad (EXACT numpy fp32 sequence) ----
  float rr[6];
#pragma unroll
  for (int n = 0; n < 6; ++n)
    rr[n] = __fadd_rn(__fmul_rn(px[n], px[n]), __fmul_rn(py[n], py[n]));
  unsigned long long mask;
  {
    const int h2 = (g >> 1) & 1, q2 = g & 1;
    float pxn[3], pyn[3], rrn[3], pxm[3], pym[3], rrm[3];
#pragma unroll
    for (int k = 0; k < 3; ++k) {
      pxn[k] = h2 ? px[k + 3] : px[k];
      pyn[k] = h2 ? py[k + 3] : py[k];
      rrn[k] = h2 ? rr[k + 3] : rr[k];
      pxm[k] = q2 ? px[k + 3] : px[k];
      pym[k] = q2 ? py[k + 3] : py[k];
      rrm[k] = q2 ? rr[k + 3] : rr[k];
    }
    unsigned long long part = 0ull;
    const int rbase = 3 * h2, mbase = 3 * q2;
#pragma unroll
    for (int k = 0; k < 3; ++k) {
#pragma unroll
      for (int j = 0; j < 3; ++j) {
        float dot = __fadd_rn(__fmul_rn(pxn[k], pxm[j]), __fmul_rn(pyn[k], pym[j]));
        float d2 = __fadd_rn(__fsub_rn(rrn[k], __fmul_rn(2.0f, dot)), rrm[j]);
        float dist = sqrtf(d2);  // exact numpy fp32 sequence; diag NaN -> false
        if (dist > 4.0f) part |= (1ull << ((rbase + k) * 6 + (mbase + j)));
      }
    }
    unsigned lo = (unsigned)part, hi = (unsigned)(part >> 32);
    lo |= qperm_u<0xB1>(lo); hi |= qperm_u<0xB1>(hi);
    lo |= qperm_u<0x4E>(lo); hi |= qperm_u<0x4E>(hi);
    mask = (unsigned long long)lo | ((unsigned long long)hi << 32);
  }

  // ---- feature extension, split across the 4 g-lanes (2 output features each) ----
  float myo[6][2];
#pragma unroll
  for (int k = 0; k < 2; ++k) {
    const int o = 2 * g + k;
    const float4 w0 = *(const float4*)(sWext + o * 8);
    const float4 w1 = *(const float4*)(sWext + o * 8 + 4);
    const float bo = sbext[o];
#pragma unroll
    for (int n = 0; n < 6; ++n) {
      float s = bo;
      s = fmaf(bfr[n][0], w0.x, s); s = fmaf(bfr[n][1], w0.y, s);
      s = fmaf(bfr[n][2], w0.z, s); s = fmaf(bfr[n][3], w0.w, s);
      s = fmaf(bfr[n][4], w1.x, s); s = fmaf(bfr[n][5], w1.y, s);
      s = fmaf(bfr[n][6], w1.z, s); s = fmaf(bfr[n][7], w1.w, s);
      myo[n][k] = fmaxf(s, 0.0f);
    }
  }
  // all-gather feat[6][8] via DPP quad broadcasts (lane j holds o=2j,2j+1)
  float feat[6][8];
#pragma unroll
  for (int n = 0; n < 6; ++n) {
    feat[n][0] = qperm_f<0x00>(myo[n][0]);
    feat[n][1] = qperm_f<0x00>(myo[n][1]);
    feat[n][2] = qperm_f<0x55>(myo[n][0]);
    feat[n][3] = qperm_f<0x55>(myo[n][1]);
    feat[n][4] = qperm_f<0xAA>(myo[n][0]);
    feat[n][5] = qperm_f<0xAA>(myo[n][1]);
    feat[n][6] = qperm_f<0xFF>(myo[n][0]);
    feat[n][7] = qperm_f<0xFF>(myo[n][1]);
  }

  // ---- con init: 0.25*bfr so the 4-lane sum contributes the residual exactly once ----
  float con[6][8];
#pragma unroll
  for (int n = 0; n < 6; ++n)
#pragma unroll
    for (int f = 0; f < 8; ++f) con[n][f] = 0.25f * bfr[n][f];

  // ---- this lane's group tables (float4 LDS reads) ----
  const float4* M4 = (const float4*)(sM + g * 68);
  const float4* W4 = (const float4*)(sWgcn + g * 68);
  const float4* U4 = (const float4*)(sU + g * 12);
  const float4* V4 = (const float4*)(sV + g * 12);
  const float Cg = sC[g];

  // z[m][f1] = sum_f2 M[f1][f2]*feat[m][f2]
  float z[6][8];
#pragma unroll
  for (int f1 = 0; f1 < 8; ++f1) {
    const float4 a = M4[2 * f1], b = M4[2 * f1 + 1];
#pragma unroll
    for (int m = 0; m < 6; ++m) {
      float s = 0.0f;
      s = fmaf(a.x, feat[m][0], s); s = fmaf(a.y, feat[m][1], s);
      s = fmaf(a.z, feat[m][2], s); s = fmaf(a.w, feat[m][3], s);
      s = fmaf(b.x, feat[m][4], s); s = fmaf(b.y, feat[m][5], s);
      s = fmaf(b.z, feat[m][6], s); s = fmaf(b.w, feat[m][7], s);
      z[m][f1] = s;
    }
  }

  float uv[6], vv[6];
  {
    const float4 u0 = U4[0], u1 = U4[1];
    const float4 v0 = V4[0], v1 = V4[1];
#pragma unroll
    for (int n = 0; n < 6; ++n) {
      float su = 0.0f, sv = 0.0f;
      su = fmaf(u0.x, feat[n][0], su); su = fmaf(u0.y, feat[n][1], su);
      su = fmaf(u0.z, feat[n][2], su); su = fmaf(u0.w, feat[n][3], su);
      su = fmaf(u1.x, feat[n][4], su); su = fmaf(u1.y, feat[n][5], su);
      su = fmaf(u1.z, feat[n][6], su); su = fmaf(u1.w, feat[n][7], su);
      sv = fmaf(v0.x, feat[n][0], sv); sv = fmaf(v0.y, feat[n][1], sv);
      sv = fmaf(v0.z, feat[n][2], sv); sv = fmaf(v0.w, feat[n][3], sv);
      sv = fmaf(v1.x, feat[n][4], sv); sv = fmaf(v1.y, feat[n][5], sv);
      sv = fmaf(v1.z, feat[n][6], sv); sv = fmaf(v1.w, feat[n][7], sv);
      uv[n] = su; vv[n] = sv;
    }
  }

  // sim + softmax -> P[6][6]
  float P[6][6];
#pragma unroll
  for (int n = 0; n < 6; ++n) {
    float simr[6];
    float rmax = -INFINITY;
#pragma unroll
    for (int m = 0; m < 6; ++m) {
      float s = 0.0f;
#pragma unroll
      for (int f = 0; f < 8; ++f) s = fmaf(feat[n][f], z[m][f], s);
      s = (s + uv[n] + vv[m] + Cg) * 0.0625f;
      const bool msk = (mask >> (n * 6 + m)) & 1ull;
      simr[m] = msk ? -INFINITY : s;
      rmax = fmaxf(rmax, simr[m]);
    }
    float e6[6], esum = 0.0f;
#pragma unroll
    for (int m = 0; m < 6; ++m) {
      float ev = __expf(simr[m] - rmax);
      e6[m] = ev; esum += ev;
    }
    const float inv = 1.0f / esum;  // diag always unmasked
#pragma unroll
    for (int m = 0; m < 6; ++m) P[n][m] = e6[m] * inv;
  }

  // agg[n][f] = sum_m P[n][m]*feat[m][f]
  float agg[6][8];
#pragma unroll
  for (int n = 0; n < 6; ++n)
#pragma unroll
    for (int f = 0; f < 8; ++f) agg[n][f] = 0.0f;
#pragma unroll
  for (int m = 0; m < 6; ++m)
#pragma unroll
    for (int f = 0; f < 8; ++f) {
      const float fv = feat[m][f];
#pragma unroll
      for (int n = 0; n < 6; ++n) agg[n][f] = fmaf(P[n][m], fv, agg[n][f]);
    }

  // con += relu(0.25*Wgcn_g @ agg)
#pragma unroll
  for (int o = 0; o < 8; ++o) {
    const float4 a = W4[2 * o], b = W4[2 * o + 1];
#pragma unroll
    for (int n = 0; n < 6; ++n) {
      float s = 0.0f;
      s = fmaf(a.x, agg[n][0], s); s = fmaf(a.y, agg[n][1], s);
      s = fmaf(a.z, agg[n][2], s); s = fmaf(a.w, agg[n][3], s);
      s = fmaf(b.x, agg[n][4], s); s = fmaf(b.y, agg[n][5], s);
      s = fmaf(b.z, agg[n][6], s); s = fmaf(b.w, agg[n][7], s);
      con[n][o] += fmaxf(s, 0.0f);
    }
  }

  // ---- butterfly-sum across the 4 g-lanes via DPP (xor1, xor2) ----
#pragma unroll
  for (int n = 0; n < 6; ++n)
#pragma unroll
    for (int f = 0; f < 8; ++f) {
      float v = con[n][f];
      v += qperm_f<0xB1>(v);
      v += qperm_f<0x4E>(v);
      con[n][f] = v;
    }

  // ---- epilogue ----
  float pooled[8];
#pragma unroll
  for (int f = 0; f < 8; ++f) {
    float mx = con[0][f];
#pragma unroll
    for (int n = 1; n < 6; ++n) mx = fmaxf(mx, con[n][f]);
    pooled[f] = mx;
  }
  float scg = sbact[g], sc4 = sbact[4];
#pragma unroll
  for (int f = 0; f < 8; ++f) {
    scg = fmaf(pooled[f], sWact[g * 8 + f], scg);
    sc4 = fmaf(pooled[f], sWact[4 * 8 + f], sc4);
  }
  const size_t ob = (size_t)e * 5;
  out[ob + g] = scg;
  if (g == 0) out[ob + 4] = sc4;
}

extern "C" void kernel_launch(void* const* d_in, const int* in_sizes, int n_in,
                              void* d_out, int out_size, void* d_ws, size_t ws_size,
                              hipStream_t stream) {
  const float* bfeat   = (const float*)d_in[0];
  const float* pos     = (const float*)d_in[1];
  const float* W_ext   = (const float*)d_in[2];
  const float* b_ext   = (const float*)d_in[3];
  const float* W_theta = (const float*)d_in[4];
  const float* b_theta = (const float*)d_in[5];
  const float* W_phi   = (const float*)d_in[6];
  const float* b_phi   = (const float*)d_in[7];
  const float* W_gcn   = (const float*)d_in[8];
  const float* W_act   = (const float*)d_in[9];
  const float* b_act   = (const float*)d_in[10];
  float* out = (float*)d_out;
  float* ws  = (float*)d_ws;

  const int B = in_sizes[0] / 48;  // [B,6,8]

  hipLaunchKernelGGL(gcn_precompute, dim3(81), dim3(256), 0, stream,
                     W_theta, b_theta, W_phi, b_phi, ws);
  const int grid = (B + 63) / 64;
  hipLaunchKernelGGL(gcn_main, dim3(grid), dim3(256), 0, stream,
                     bfeat, pos, W_ext, b_ext, W_gcn, W_act, b_act, ws, out, B);
}